// Round 2
// baseline (2045.731 us; speedup 1.0000x reference)
//
#include <hip/hip_runtime.h>
#include <cstdint>

// ---------------------------------------------------------------------------
// DDPM + VAE query encoder, MI355X round 2 (fp32)
// Change vs r1: JAX >=0.4.36 defaults jax_threefry_partitionable=True.
// random_bits(32) semantics: per-element uint64 counter i (hi=0, lo=i here),
// bits_i = o0 ^ o1 of threefry2x32(key, (hi, lo)).  fold_in unchanged:
// new_key = threefry(key, (0, t)).
// ---------------------------------------------------------------------------

#define DEVI __device__ __forceinline__

DEVI uint32_t rotl32(uint32_t x, uint32_t r) { return (x << r) | (x >> (32u - r)); }

// JAX/Random123 threefry2x32, 20 rounds.
DEVI void threefry2x32(uint32_t k0, uint32_t k1, uint32_t x0, uint32_t x1,
                       uint32_t &o0, uint32_t &o1)
{
  const uint32_t ks2 = k0 ^ k1 ^ 0x1BD11BDAu;
  x0 += k0; x1 += k1;
#define TFR(r) { x0 += x1; x1 = rotl32(x1, r); x1 ^= x0; }
  TFR(13u) TFR(15u) TFR(26u) TFR(6u)   x0 += k1;  x1 += ks2 + 1u;
  TFR(17u) TFR(29u) TFR(16u) TFR(24u)  x0 += ks2; x1 += k0 + 2u;
  TFR(13u) TFR(15u) TFR(26u) TFR(6u)   x0 += k0;  x1 += k1 + 3u;
  TFR(17u) TFR(29u) TFR(16u) TFR(24u)  x0 += k1;  x1 += ks2 + 4u;
  TFR(13u) TFR(15u) TFR(26u) TFR(6u)   x0 += ks2; x1 += k0 + 5u;
#undef TFR
  o0 = x0; o1 = x1;
}

// partitionable random_bits(32) for flat index j (size < 2^32 -> hi word 0)
DEVI uint32_t jax_random_bits32(uint32_t k0, uint32_t k1, uint32_t j)
{
  uint32_t a, b;
  threefry2x32(k0, k1, 0u, j, a, b);
  return a ^ b;
}

// Matches jax.random.normal f32: bits -> uniform in [nextafter(-1,0), 1) ->
// sqrt(2) * erf_inv (XLA/Giles polynomial).
DEVI float jax_bits_to_normal(uint32_t bits)
{
  const float LO = -0.99999994f;              // nextafter(-1,0) in f32
  float f = __uint_as_float((bits >> 9) | 0x3f800000u) - 1.0f;
  float u = fmaxf(LO, f * 2.0f + LO);         // (hi-lo) rounds to exactly 2.0f
  float w = -log1pf(-u * u);
  float p;
  if (w < 5.0f) {
    w = w - 2.5f;
    p =              2.81022636e-08f;
    p = fmaf(p, w,   3.43273939e-07f);
    p = fmaf(p, w,  -3.5233877e-06f);
    p = fmaf(p, w,  -4.39150654e-06f);
    p = fmaf(p, w,   0.00021858087f);
    p = fmaf(p, w,  -0.00125372503f);
    p = fmaf(p, w,  -0.00417768164f);
    p = fmaf(p, w,   0.246640727f);
    p = fmaf(p, w,   1.50140941f);
  } else {
    w = sqrtf(w) - 3.0f;
    p =             -0.000200214257f;
    p = fmaf(p, w,   0.000100950558f);
    p = fmaf(p, w,   0.00134934322f);
    p = fmaf(p, w,  -0.00367342844f);
    p = fmaf(p, w,   0.00573950773f);
    p = fmaf(p, w,  -0.0076224613f);
    p = fmaf(p, w,   0.00943887047f);
    p = fmaf(p, w,   1.00167406f);
    p = fmaf(p, w,   2.83297682f);
  }
  return 1.41421356237f * (p * u);            // sqrt(2) * (p * u)
}

// ---------------------------------------------------------------------------
// K_pool: 2048 blocks x 256 threads; wave per row, lane per dim.
__global__ __launch_bounds__(256)
void k_pool(const int* __restrict__ seq, const float* __restrict__ emb,
            float* __restrict__ pooled)
{
  const int lane = threadIdx.x & 63;
  const int r    = blockIdx.x * 4 + (threadIdx.x >> 6);   // 0..8191
  const int* row = seq + r * 100;
  float s = 0.f;
  int cnt = 0;
  for (int l = 0; l < 100; ++l) {
    int id = row[l];
    cnt += (id != 0);
    s += emb[id * 64 + lane];
  }
  pooled[r * 64 + lane] = s / sqrtf((float)cnt);
}

// ---------------------------------------------------------------------------
// K_enc: 1024 blocks x 256 threads; 8 rows per block.
__global__ __launch_bounds__(256)
void k_enc(const float* __restrict__ pooled,
           const float* __restrict__ W1, const float* __restrict__ b1,
           const float* __restrict__ W2, const float* __restrict__ b2,
           const float* __restrict__ Wc, const float* __restrict__ bc,
           float* __restrict__ cproj)
{
  __shared__ float p_s[8][64];
  __shared__ float h_s[8][256];
  __shared__ float mu_s[8][64];
  const int tid = threadIdx.x;
  const int r0  = blockIdx.x * 8;

  for (int i = tid; i < 8 * 64; i += 256)
    p_s[i >> 6][i & 63] = pooled[r0 * 64 + i];
  __syncthreads();

  // layer 1: thread j = tid computes h[r][j] for all 8 rows
  float hacc[8];
#pragma unroll
  for (int r = 0; r < 8; ++r) hacc[r] = b1[tid];
  for (int k = 0; k < 64; ++k) {
    float w = W1[k * 256 + tid];
#pragma unroll
    for (int r = 0; r < 8; ++r) hacc[r] = fmaf(p_s[r][k], w, hacc[r]);
  }
#pragma unroll
  for (int r = 0; r < 8; ++r) h_s[r][tid] = fmaxf(hacc[r], 0.f);
  __syncthreads();

  // layer 2 (only first 64 of 128 outputs -> mu): tasks (r, j)
#pragma unroll
  for (int pass = 0; pass < 2; ++pass) {
    int r = pass * 4 + (tid >> 6);
    int j = tid & 63;
    float acc = b2[j];
    for (int k = 0; k < 256; ++k)
      acc = fmaf(h_s[r][k], W2[k * 128 + j], acc);
    mu_s[r][j] = acc;
  }
  __syncthreads();

  // cond projection: cproj = mu @ Wc + bc
#pragma unroll
  for (int pass = 0; pass < 2; ++pass) {
    int r = pass * 4 + (tid >> 6);
    int j = tid & 63;
    float acc = bc[j];
    for (int k = 0; k < 64; ++k)
      acc = fmaf(mu_s[r][k], Wc[k * 64 + j], acc);
    cproj[(r0 + r) * 64 + j] = acc;
  }
}

// ---------------------------------------------------------------------------
// K_sched: single thread, f32 mimic of the jnp schedule.
// layout: sched[0..199]=sqrt_recip, [200..399]=sqrt_recipm1,
//         [400..599]=coef1, [600..799]=coef2, [800..999]=sigma
__global__ void k_sched(float* __restrict__ sched)
{
  if (threadIdx.x != 0 || blockIdx.x != 0) return;
  const float start = (float)(5.0 * 1e-4);
  const float stop  = (float)(5.0 * 0.02);
  const float delta = stop - start;
  float prod = 1.f;
  for (int i = 0; i < 200; ++i) {
    float beta  = start + ((float)i * delta) / 199.0f;
    float alpha = 1.0f - beta;
    float acp_prev = prod;
    prod = prod * alpha;                 // acp[i]
    float acp = prod;
    float om  = 1.0f - acp;
    sched[i]       = sqrtf(1.0f / acp);
    sched[200 + i] = sqrtf(1.0f / acp - 1.0f);
    sched[400 + i] = beta * sqrtf(acp_prev) / om;
    sched[600 + i] = (1.0f - acp_prev) * sqrtf(alpha) / om;
    float pv = beta * (1.0f - acp_prev) / om;
    sched[800 + i] = (i > 0) ? sqrtf(pv) : 0.0f;
  }
}

// ---------------------------------------------------------------------------
// K_tproj: 200 blocks x 64 threads; tpb[t][d] = temb(t)@W_t + b_t + b_in
__global__ __launch_bounds__(64)
void k_tproj(const float* __restrict__ Wt, const float* __restrict__ bt,
             const float* __restrict__ bin, float* __restrict__ tpb)
{
  __shared__ float temb[64];
  const int t = blockIdx.x;
  const int d = threadIdx.x;
  const float lg = logf(10000.0f);
  {
    int i = d & 31;
    float fr  = expf((-lg * (float)i) / 32.0f);
    float ang = (float)t * fr;
    temb[d] = (d < 32) ? cosf(ang) : sinf(ang);
  }
  __syncthreads();
  float acc = bt[d] + bin[d];
  for (int k = 0; k < 64; ++k)
    acc = fmaf(temb[k], Wt[k * 64 + d], acc);
  tpb[t * 64 + d] = acc;
}

// ---------------------------------------------------------------------------
// K_ddpm: 1024 blocks x 256 threads; wave handles rows (p, p+4096), lane = dim.
__global__ __launch_bounds__(256)
void k_ddpm(const float* __restrict__ Win, const float* __restrict__ Wout,
            const float* __restrict__ bout,
            const float* __restrict__ cproj, const float* __restrict__ tpb,
            const float* __restrict__ sched, float* __restrict__ out)
{
  const int lane = threadIdx.x & 63;
  const int p    = blockIdx.x * 4 + (threadIdx.x >> 6);    // 0..4095
  const uint32_t jA = (uint32_t)(p * 64 + lane);           // flat idx, < 262144
  const uint32_t jB = jA + 262144u;                        // row p+4096

  float Wi[64], Wo[64];
#pragma unroll
  for (int k = 0; k < 64; ++k) Wi[k] = Win[k * 64 + lane];
#pragma unroll
  for (int k = 0; k < 64; ++k) Wo[k] = Wout[k * 64 + lane];
  const float bo  = bout[lane];
  const float cpA = cproj[p * 64 + lane];
  const float cpB = cproj[(p + 4096) * 64 + lane];

  // x_init = normal(key(1)=[0,1]), partitionable bits
  float xA = jax_bits_to_normal(jax_random_bits32(0u, 1u, jA));
  float xB = jax_bits_to_normal(jax_random_bits32(0u, 1u, jB));

  const float* sr_a   = sched;
  const float* srm1_a = sched + 200;
  const float* c1_a   = sched + 400;
  const float* c2_a   = sched + 600;
  const float* sg_a   = sched + 800;

#pragma unroll 1
  for (int t = 199; t >= 0; --t) {
    // fold_in(key(2)=[0,2], t) = threefry(key=[0,2], x=[0,t])  (wave-uniform -> SALU)
    uint32_t fk0, fk1;
    threefry2x32(0u, 2u, 0u, (uint32_t)t, fk0, fk1);

    const float tp = tpb[t * 64 + lane];
    float aA = tp + cpA;
    float aB = tp + cpB;
    {
      int xiA = __float_as_int(xA), xiB = __float_as_int(xB);
#pragma unroll
      for (int k = 0; k < 64; ++k) {
        float xak = __int_as_float(__builtin_amdgcn_readlane(xiA, k));
        float xbk = __int_as_float(__builtin_amdgcn_readlane(xiB, k));
        aA = fmaf(xak, Wi[k], aA);
        aB = fmaf(xbk, Wi[k], aB);
      }
    }
    // silu
    float hA = aA / (1.0f + __expf(-aA));
    float hB = aB / (1.0f + __expf(-aB));

    float eA = bo, eB = bo;
    {
      int hiA = __float_as_int(hA), hiB = __float_as_int(hB);
#pragma unroll
      for (int k = 0; k < 64; ++k) {
        float hak = __int_as_float(__builtin_amdgcn_readlane(hiA, k));
        float hbk = __int_as_float(__builtin_amdgcn_readlane(hiB, k));
        eA = fmaf(hak, Wo[k], eA);
        eB = fmaf(hbk, Wo[k], eB);
      }
    }

    const float sr = sr_a[t], srm1 = srm1_a[t];
    const float c1 = c1_a[t], c2 = c2_a[t], sg = sg_a[t];

    float x0A = fminf(1.f, fmaxf(-1.f, sr * xA - srm1 * eA));
    float x0B = fminf(1.f, fmaxf(-1.f, sr * xB - srm1 * eB));

    float nA = jax_bits_to_normal(jax_random_bits32(fk0, fk1, jA));
    float nB = jax_bits_to_normal(jax_random_bits32(fk0, fk1, jB));

    xA = c1 * x0A + c2 * xA + sg * nA;
    xB = c1 * x0B + c2 * xB + sg * nB;
  }

  out[p * 64 + lane]            = xA;
  out[(p + 4096) * 64 + lane]   = xB;
}

// ---------------------------------------------------------------------------
extern "C" void kernel_launch(void* const* d_in, const int* in_sizes, int n_in,
                              void* d_out, int out_size, void* d_ws, size_t ws_size,
                              hipStream_t stream)
{
  const int*   seq  = (const int*)  d_in[0];
  const float* emb  = (const float*)d_in[1];
  const float* W1   = (const float*)d_in[2];
  const float* b1   = (const float*)d_in[3];
  const float* W2   = (const float*)d_in[4];
  const float* b2   = (const float*)d_in[5];
  const float* Win  = (const float*)d_in[6];
  const float* bin  = (const float*)d_in[7];
  const float* Wt   = (const float*)d_in[8];
  const float* bt   = (const float*)d_in[9];
  const float* Wc   = (const float*)d_in[10];
  const float* bc   = (const float*)d_in[11];
  const float* Wout = (const float*)d_in[12];
  const float* bout = (const float*)d_in[13];

  float* out   = (float*)d_out;
  float* ws    = (float*)d_ws;
  float* cproj = ws;                       // 524288 floats
  float* tpb   = ws + 524288;              // 12800 floats
  float* sched = ws + 524288 + 12800;      // 1000 floats
  float* pooled = out;                     // reuse d_out as scratch (overwritten later)

  k_pool <<<2048, 256, 0, stream>>>(seq, emb, pooled);
  k_enc  <<<1024, 256, 0, stream>>>(pooled, W1, b1, W2, b2, Wc, bc, cproj);
  k_sched<<<1, 64, 0, stream>>>(sched);
  k_tproj<<<200, 64, 0, stream>>>(Wt, bt, bin, tpb);
  k_ddpm <<<1024, 256, 0, stream>>>(Win, Wout, bout, cproj, tpb, sched, out);
}

// Round 3
// 1689.190 us; speedup vs baseline: 1.2111x; 1.2111x over previous
//
#include <hip/hip_runtime.h>
#include <cstdint>

// ---------------------------------------------------------------------------
// DDPM + VAE query encoder, MI355X round 3 (fp32)
// Changes vs r2:
//  - k_ddpm: pin Wi[64]/Wo[64] in VGPRs via empty-asm (compiler was sinking
//    the weight loads into the 200-step loop: VGPR=88, FETCH=1.5GB).
//    __launch_bounds__(256,2) -> VGPR cap 256 (need ~180).
//  - cheaper erfinv log: -log((1-u)(1+u)) via v_log_f32 (no cancellation).
//  - silu via v_rcp_f32 instead of precise divide.
// ---------------------------------------------------------------------------

#define DEVI __device__ __forceinline__

DEVI uint32_t rotl32(uint32_t x, uint32_t r) { return (x << r) | (x >> (32u - r)); }

// JAX/Random123 threefry2x32, 20 rounds.
DEVI void threefry2x32(uint32_t k0, uint32_t k1, uint32_t x0, uint32_t x1,
                       uint32_t &o0, uint32_t &o1)
{
  const uint32_t ks2 = k0 ^ k1 ^ 0x1BD11BDAu;
  x0 += k0; x1 += k1;
#define TFR(r) { x0 += x1; x1 = rotl32(x1, r); x1 ^= x0; }
  TFR(13u) TFR(15u) TFR(26u) TFR(6u)   x0 += k1;  x1 += ks2 + 1u;
  TFR(17u) TFR(29u) TFR(16u) TFR(24u)  x0 += ks2; x1 += k0 + 2u;
  TFR(13u) TFR(15u) TFR(26u) TFR(6u)   x0 += k0;  x1 += k1 + 3u;
  TFR(17u) TFR(29u) TFR(16u) TFR(24u)  x0 += k1;  x1 += ks2 + 4u;
  TFR(13u) TFR(15u) TFR(26u) TFR(6u)   x0 += ks2; x1 += k0 + 5u;
#undef TFR
  o0 = x0; o1 = x1;
}

// partitionable random_bits(32) for flat index j (size < 2^32 -> hi word 0)
DEVI uint32_t jax_random_bits32(uint32_t k0, uint32_t k1, uint32_t j)
{
  uint32_t a, b;
  threefry2x32(k0, k1, 0u, j, a, b);
  return a ^ b;
}

// bits -> uniform [-1+eps, 1) -> sqrt(2)*erfinv(u) (XLA/Giles polynomial).
// log1p(-u^2) computed as log((1-u)(1+u)) -- cancellation-free.
DEVI float jax_bits_to_normal(uint32_t bits)
{
  const float LO = -0.99999994f;              // nextafter(-1,0) in f32
  float f = __uint_as_float((bits >> 9) | 0x3f800000u) - 1.0f;
  float u = fmaxf(LO, f * 2.0f + LO);
  float w = -__logf((1.0f - u) * (1.0f + u));
  float p;
  if (w < 5.0f) {
    w = w - 2.5f;
    p =              2.81022636e-08f;
    p = fmaf(p, w,   3.43273939e-07f);
    p = fmaf(p, w,  -3.5233877e-06f);
    p = fmaf(p, w,  -4.39150654e-06f);
    p = fmaf(p, w,   0.00021858087f);
    p = fmaf(p, w,  -0.00125372503f);
    p = fmaf(p, w,  -0.00417768164f);
    p = fmaf(p, w,   0.246640727f);
    p = fmaf(p, w,   1.50140941f);
  } else {
    w = sqrtf(w) - 3.0f;
    p =             -0.000200214257f;
    p = fmaf(p, w,   0.000100950558f);
    p = fmaf(p, w,   0.00134934322f);
    p = fmaf(p, w,  -0.00367342844f);
    p = fmaf(p, w,   0.00573950773f);
    p = fmaf(p, w,  -0.0076224613f);
    p = fmaf(p, w,   0.00943887047f);
    p = fmaf(p, w,   1.00167406f);
    p = fmaf(p, w,   2.83297682f);
  }
  return 1.41421356237f * (p * u);
}

// ---------------------------------------------------------------------------
// K_pool: 2048 blocks x 256 threads; wave per row, lane per dim.
__global__ __launch_bounds__(256)
void k_pool(const int* __restrict__ seq, const float* __restrict__ emb,
            float* __restrict__ pooled)
{
  const int lane = threadIdx.x & 63;
  const int r    = blockIdx.x * 4 + (threadIdx.x >> 6);   // 0..8191
  const int* row = seq + r * 100;
  float s = 0.f;
  int cnt = 0;
  for (int l = 0; l < 100; ++l) {
    int id = row[l];
    cnt += (id != 0);
    s += emb[id * 64 + lane];
  }
  pooled[r * 64 + lane] = s / sqrtf((float)cnt);
}

// ---------------------------------------------------------------------------
// K_enc: 1024 blocks x 256 threads; 8 rows per block.
__global__ __launch_bounds__(256)
void k_enc(const float* __restrict__ pooled,
           const float* __restrict__ W1, const float* __restrict__ b1,
           const float* __restrict__ W2, const float* __restrict__ b2,
           const float* __restrict__ Wc, const float* __restrict__ bc,
           float* __restrict__ cproj)
{
  __shared__ float p_s[8][64];
  __shared__ float h_s[8][256];
  __shared__ float mu_s[8][64];
  const int tid = threadIdx.x;
  const int r0  = blockIdx.x * 8;

  for (int i = tid; i < 8 * 64; i += 256)
    p_s[i >> 6][i & 63] = pooled[r0 * 64 + i];
  __syncthreads();

  float hacc[8];
#pragma unroll
  for (int r = 0; r < 8; ++r) hacc[r] = b1[tid];
  for (int k = 0; k < 64; ++k) {
    float w = W1[k * 256 + tid];
#pragma unroll
    for (int r = 0; r < 8; ++r) hacc[r] = fmaf(p_s[r][k], w, hacc[r]);
  }
#pragma unroll
  for (int r = 0; r < 8; ++r) h_s[r][tid] = fmaxf(hacc[r], 0.f);
  __syncthreads();

#pragma unroll
  for (int pass = 0; pass < 2; ++pass) {
    int r = pass * 4 + (tid >> 6);
    int j = tid & 63;
    float acc = b2[j];
    for (int k = 0; k < 256; ++k)
      acc = fmaf(h_s[r][k], W2[k * 128 + j], acc);
    mu_s[r][j] = acc;
  }
  __syncthreads();

#pragma unroll
  for (int pass = 0; pass < 2; ++pass) {
    int r = pass * 4 + (tid >> 6);
    int j = tid & 63;
    float acc = bc[j];
    for (int k = 0; k < 64; ++k)
      acc = fmaf(mu_s[r][k], Wc[k * 64 + j], acc);
    cproj[(r0 + r) * 64 + j] = acc;
  }
}

// ---------------------------------------------------------------------------
// K_sched: single thread, f32 mimic of the jnp schedule.
__global__ void k_sched(float* __restrict__ sched)
{
  if (threadIdx.x != 0 || blockIdx.x != 0) return;
  const float start = (float)(5.0 * 1e-4);
  const float stop  = (float)(5.0 * 0.02);
  const float delta = stop - start;
  float prod = 1.f;
  for (int i = 0; i < 200; ++i) {
    float beta  = start + ((float)i * delta) / 199.0f;
    float alpha = 1.0f - beta;
    float acp_prev = prod;
    prod = prod * alpha;
    float acp = prod;
    float om  = 1.0f - acp;
    sched[i]       = sqrtf(1.0f / acp);
    sched[200 + i] = sqrtf(1.0f / acp - 1.0f);
    sched[400 + i] = beta * sqrtf(acp_prev) / om;
    sched[600 + i] = (1.0f - acp_prev) * sqrtf(alpha) / om;
    float pv = beta * (1.0f - acp_prev) / om;
    sched[800 + i] = (i > 0) ? sqrtf(pv) : 0.0f;
  }
}

// ---------------------------------------------------------------------------
// K_tproj: 200 blocks x 64 threads; tpb[t][d] = temb(t)@W_t + b_t + b_in
__global__ __launch_bounds__(64)
void k_tproj(const float* __restrict__ Wt, const float* __restrict__ bt,
             const float* __restrict__ bin, float* __restrict__ tpb)
{
  __shared__ float temb[64];
  const int t = blockIdx.x;
  const int d = threadIdx.x;
  const float lg = logf(10000.0f);
  {
    int i = d & 31;
    float fr  = expf((-lg * (float)i) / 32.0f);
    float ang = (float)t * fr;
    temb[d] = (d < 32) ? cosf(ang) : sinf(ang);
  }
  __syncthreads();
  float acc = bt[d] + bin[d];
  for (int k = 0; k < 64; ++k)
    acc = fmaf(temb[k], Wt[k * 64 + d], acc);
  tpb[t * 64 + d] = acc;
}

// ---------------------------------------------------------------------------
// K_ddpm: 1024 blocks x 256 threads; wave handles rows (p, p+4096), lane = dim.
// __launch_bounds__(256,2): VGPR cap 256 so the 128 pinned weight regs fit.
__global__ __launch_bounds__(256, 2)
void k_ddpm(const float* __restrict__ Win, const float* __restrict__ Wout,
            const float* __restrict__ bout,
            const float* __restrict__ cproj, const float* __restrict__ tpb,
            const float* __restrict__ sched, float* __restrict__ out)
{
  const int lane = threadIdx.x & 63;
  const int p    = blockIdx.x * 4 + (threadIdx.x >> 6);    // 0..4095
  const uint32_t jA = (uint32_t)(p * 64 + lane);           // flat idx, < 262144
  const uint32_t jB = jA + 262144u;                        // row p+4096

  float Wi[64], Wo[64];
#pragma unroll
  for (int k = 0; k < 64; ++k) Wi[k] = Win[k * 64 + lane];
#pragma unroll
  for (int k = 0; k < 64; ++k) Wo[k] = Wout[k * 64 + lane];
  // Pin in VGPRs: opaque to the optimizer -> cannot rematerialize the loads
  // inside the 200-step loop (r2: compiler sank them, FETCH_SIZE=1.5GB).
#pragma unroll
  for (int k = 0; k < 64; ++k) {
    asm volatile("" : "+v"(Wi[k]));
    asm volatile("" : "+v"(Wo[k]));
  }

  const float bo  = bout[lane];
  const float cpA = cproj[p * 64 + lane];
  const float cpB = cproj[(p + 4096) * 64 + lane];

  // x_init = normal(key(1)=[0,1]), partitionable bits
  float xA = jax_bits_to_normal(jax_random_bits32(0u, 1u, jA));
  float xB = jax_bits_to_normal(jax_random_bits32(0u, 1u, jB));

  const float* sr_a   = sched;
  const float* srm1_a = sched + 200;
  const float* c1_a   = sched + 400;
  const float* c2_a   = sched + 600;
  const float* sg_a   = sched + 800;

#pragma unroll 1
  for (int t = 199; t >= 0; --t) {
    // fold_in(key(2), t): wave-uniform -> SALU, overlaps VALU
    uint32_t fk0, fk1;
    threefry2x32(0u, 2u, 0u, (uint32_t)t, fk0, fk1);

    const float tp = tpb[t * 64 + lane];
    float aA = tp + cpA;
    float aB = tp + cpB;
    {
      int xiA = __float_as_int(xA), xiB = __float_as_int(xB);
#pragma unroll
      for (int k = 0; k < 64; ++k) {
        float xak = __int_as_float(__builtin_amdgcn_readlane(xiA, k));
        float xbk = __int_as_float(__builtin_amdgcn_readlane(xiB, k));
        aA = fmaf(xak, Wi[k], aA);
        aB = fmaf(xbk, Wi[k], aB);
      }
    }
    // silu via fast rcp (~1 ulp)
    float hA = aA * __builtin_amdgcn_rcpf(1.0f + __expf(-aA));
    float hB = aB * __builtin_amdgcn_rcpf(1.0f + __expf(-aB));

    float eA = bo, eB = bo;
    {
      int hiA = __float_as_int(hA), hiB = __float_as_int(hB);
#pragma unroll
      for (int k = 0; k < 64; ++k) {
        float hak = __int_as_float(__builtin_amdgcn_readlane(hiA, k));
        float hbk = __int_as_float(__builtin_amdgcn_readlane(hiB, k));
        eA = fmaf(hak, Wo[k], eA);
        eB = fmaf(hbk, Wo[k], eB);
      }
    }

    const float sr = sr_a[t], srm1 = srm1_a[t];
    const float c1 = c1_a[t], c2 = c2_a[t], sg = sg_a[t];

    float x0A = fminf(1.f, fmaxf(-1.f, sr * xA - srm1 * eA));
    float x0B = fminf(1.f, fmaxf(-1.f, sr * xB - srm1 * eB));

    float nA = jax_bits_to_normal(jax_random_bits32(fk0, fk1, jA));
    float nB = jax_bits_to_normal(jax_random_bits32(fk0, fk1, jB));

    xA = c1 * x0A + c2 * xA + sg * nA;
    xB = c1 * x0B + c2 * xB + sg * nB;
  }

  out[p * 64 + lane]            = xA;
  out[(p + 4096) * 64 + lane]   = xB;
}

// ---------------------------------------------------------------------------
extern "C" void kernel_launch(void* const* d_in, const int* in_sizes, int n_in,
                              void* d_out, int out_size, void* d_ws, size_t ws_size,
                              hipStream_t stream)
{
  const int*   seq  = (const int*)  d_in[0];
  const float* emb  = (const float*)d_in[1];
  const float* W1   = (const float*)d_in[2];
  const float* b1   = (const float*)d_in[3];
  const float* W2   = (const float*)d_in[4];
  const float* b2   = (const float*)d_in[5];
  const float* Win  = (const float*)d_in[6];
  const float* bin  = (const float*)d_in[7];
  const float* Wt   = (const float*)d_in[8];
  const float* bt   = (const float*)d_in[9];
  const float* Wc   = (const float*)d_in[10];
  const float* bc   = (const float*)d_in[11];
  const float* Wout = (const float*)d_in[12];
  const float* bout = (const float*)d_in[13];

  float* out   = (float*)d_out;
  float* ws    = (float*)d_ws;
  float* cproj = ws;                       // 524288 floats
  float* tpb   = ws + 524288;              // 12800 floats
  float* sched = ws + 524288 + 12800;      // 1000 floats
  float* pooled = out;                     // reuse d_out as scratch

  k_pool <<<2048, 256, 0, stream>>>(seq, emb, pooled);
  k_enc  <<<1024, 256, 0, stream>>>(pooled, W1, b1, W2, b2, Wc, bc, cproj);
  k_sched<<<1, 64, 0, stream>>>(sched);
  k_tproj<<<200, 64, 0, stream>>>(Wt, bt, bin, tpb);
  k_ddpm <<<1024, 256, 0, stream>>>(Win, Wout, bout, cproj, tpb, sched, out);
}